// Round 6
// baseline (89.871 us; speedup 1.0000x reference)
//
#include <hip/hip_runtime.h>
#include <hip/hip_bf16.h>
#include <stdint.h>

#define NR   4096
#define DIM  1024
#define NE   8
#define BM   128
#define BN   128
#define BK2  32

typedef __attribute__((ext_vector_type(8))) short  bf16x8;
typedef __attribute__((ext_vector_type(8))) ushort u16x8;
typedef __attribute__((ext_vector_type(4))) float  f32x4;

__device__ __forceinline__ ushort f2bf(float f) {
    union { __hip_bfloat16 h; ushort u; } cv;
    cv.h = __float2bfloat16(f);   // RNE
    return cv.u;
}

__device__ __forceinline__ void gload16(const void* g, void* l) {
    __builtin_amdgcn_global_load_lds(
        (const __attribute__((address_space(1))) unsigned int*)g,
        (__attribute__((address_space(3))) unsigned int*)l, 16, 0, 0);
}

// ---------------- K1: WT transpose (blocks 0..7) + zero out (blocks 8..519) --
__global__ __launch_bounds__(256)
void k1_prep(const float* __restrict__ Wg, const float* __restrict__ Wn,
             float* __restrict__ WT, float* __restrict__ out) {
    const int tid = threadIdx.x;
    if (blockIdx.x < 8) {
        const int k    = blockIdx.x * 128 + (tid >> 1);
        const int half = tid & 1;                     // 0 = Wg, 1 = Wn
        const float* src = half ? Wn : Wg;
        const float4* s4 = (const float4*)(src + (size_t)k * NE);
        float4 a = s4[0], b = s4[1];
        float* d = WT + (size_t)half * 8 * DIM;
        d[(size_t)0 * DIM + k] = a.x; d[(size_t)1 * DIM + k] = a.y;
        d[(size_t)2 * DIM + k] = a.z; d[(size_t)3 * DIM + k] = a.w;
        d[(size_t)4 * DIM + k] = b.x; d[(size_t)5 * DIM + k] = b.y;
        d[(size_t)6 * DIM + k] = b.z; d[(size_t)7 * DIM + k] = b.w;
    } else {
        const int vb = blockIdx.x - 8;                // 0..511
        float4 z = {0.f, 0.f, 0.f, 0.f};
        for (int i = vb * 256 + tid; i < NR * DIM / 4; i += 512 * 256)
            ((float4*)out)[i] = z;
    }
}

// ---------------- K2: We convert+transpose (blocks 0..2047) | gate (2048..3071)
__global__ __launch_bounds__(256)
void k2_main(const float* __restrict__ We, ushort* __restrict__ WeT,
             const float* __restrict__ x, const float* __restrict__ noise,
             const float* __restrict__ WT, ushort* __restrict__ xbf,
             uint32_t* __restrict__ eid, float2* __restrict__ wpair) {
    __shared__ float smem[64 * 68];                   // 17.4 KB, both roles
    const int tid = threadIdx.x;
    if (blockIdx.x < 2048) {
        // ---- conv role: We [e][k][c] f32 -> WeT [e][c][k] bf16 ----
        const int b  = blockIdx.x;                    // e*256 + kt*16 + ct
        const int e  = b >> 8, kt = (b >> 4) & 15, ct = b & 15;
        const float* src = We + ((size_t)e * DIM + (size_t)kt * 64) * DIM + ct * 64;
#pragma unroll
        for (int j = 0; j < 4; ++j) {
            int idx = tid + j * 256;
            int r = idx >> 4, c4 = idx & 15;
            *(float4*)&smem[r * 68 + c4 * 4] = *(const float4*)(src + (size_t)r * DIM + c4 * 4);
        }
        __syncthreads();
        ushort* dst = WeT + ((size_t)e * DIM + (size_t)ct * 64) * DIM + kt * 64;
#pragma unroll
        for (int j = 0; j < 2; ++j) {
            int u = tid + j * 256;
            int c = u >> 3, ch = u & 7;
            ushort tmp[8];
#pragma unroll
            for (int q = 0; q < 8; ++q) tmp[q] = f2bf(smem[(ch * 8 + q) * 68 + c]);
            *(u16x8*)(dst + (size_t)c * DIM + ch * 8) = *(u16x8*)tmp;
        }
    } else {
        // ---- gate role (v5 body): one wave per row, no atomics ----
        const int w = tid >> 6, l = tid & 63;
        const int row = (blockIdx.x - 2048) * 4 + w;
        const float* xr = x + (size_t)row * DIM;

        float4 xv[4];
#pragma unroll
        for (int q = 0; q < 4; ++q) xv[q] = *(const float4*)(xr + q * 256 + l * 4);
#pragma unroll
        for (int q = 0; q < 4; ++q) {
            ushort4 xb;
            xb.x = f2bf(xv[q].x); xb.y = f2bf(xv[q].y);
            xb.z = f2bf(xv[q].z); xb.w = f2bf(xv[q].w);
            *(ushort4*)(xbf + (size_t)row * DIM + q * 256 + l * 4) = xb;
        }

        float acc[16];
#pragma unroll
        for (int u = 0; u < 16; ++u) {
            const float* wr_ = WT + (size_t)u * DIM + l * 4;
            float s = 0.f;
#pragma unroll
            for (int q = 0; q < 4; ++q) {
                float4 wv = *(const float4*)(wr_ + q * 256);
                s += xv[q].x * wv.x + xv[q].y * wv.y + xv[q].z * wv.z + xv[q].w * wv.w;
            }
            acc[u] = s;
        }
        // red(w,l,u) = smem[(w*64+l)*17 + u]
#pragma unroll
        for (int u = 0; u < 16; ++u) smem[(w * 64 + l) * 17 + u] = acc[u];
        asm volatile("s_waitcnt lgkmcnt(0)" ::: "memory");
        const int c = l >> 4, u = l & 15;
        float v = 0.f;
#pragma unroll
        for (int i = 0; i < 16; ++i) v += smem[(w * 64 + c * 16 + i) * 17 + u];
        v += __shfl_xor(v, 16, 64);
        v += __shfl_xor(v, 32, 64);

        const int e = l & 7;
        float ag = __shfl(v, e, 64);
        float an = __shfl(v, e + 8, 64);
        float sp = (an > 0.f) ? (an + log1pf(expf(-an))) : log1pf(expf(an));
        float H  = ag + noise[e] * sp;

        float Hh[8];
#pragma unroll
        for (int k = 0; k < 8; ++k) Hh[k] = __shfl(H, k, 64);
        if (l == 0) {
            int e0 = 0; float v0 = Hh[0];
#pragma unroll
            for (int k = 1; k < 8; ++k) if (Hh[k] > v0) { v0 = Hh[k]; e0 = k; }
            int e1 = -1; float v1 = 0.f;
#pragma unroll
            for (int k = 0; k < 8; ++k)
                if (k != e0 && (e1 < 0 || Hh[k] > v1)) { v1 = Hh[k]; e1 = k; }
            float rr = expf(v1 - v0);
            float w0 = 1.f / (1.f + rr), w1 = 1.f - w0;
            eid[row] = (uint32_t)e0 | ((uint32_t)e1 << 8);
            float2 wp; wp.x = w0; wp.y = w1;
            wpair[row] = wp;
        }
    }
}

// ---------------- bucket build: deterministic compaction ---------------------
__global__ __launch_bounds__(1024)
void bucket_build(const uint32_t* __restrict__ eid, const float2* __restrict__ wpair,
                  int* __restrict__ cnt, int* __restrict__ idxl, float* __restrict__ wl) {
    const int bucket = blockIdx.x;          // 0..15
    const int slot = bucket >> 3, ex = bucket & 7;
    __shared__ int base;
    __shared__ int wsum[16];
    if (threadIdx.x == 0) base = 0;
    const int wid = threadIdx.x >> 6, lane = threadIdx.x & 63;
    int* bidx = idxl + (size_t)bucket * NR;
    float* bwl = wl + (size_t)bucket * NR;

    for (int c0 = 0; c0 < NR; c0 += 1024) {
        const int row = c0 + threadIdx.x;
        const uint32_t em = eid[row];
        const int e = slot ? (int)((em >> 8) & 255u) : (int)(em & 255u);
        const bool m = (e == ex);
        const unsigned long long bal = __ballot(m);
        if (lane == 0) wsum[wid] = __popcll(bal);
        __syncthreads();
        int wbase = base;
        for (int i = 0; i < wid; ++i) wbase += wsum[i];
        const int pos = wbase + __popcll(bal & ((1ull << lane) - 1ull));
        if (m) {
            bidx[pos] = row;
            float2 wp = wpair[row];
            bwl[pos]  = slot ? wp.y : wp.x;
        }
        __syncthreads();
        if (threadIdx.x == 0) {
            int s = 0;
#pragma unroll
            for (int i = 0; i < 16; ++i) s += wsum[i];
            base += s;
        }
        __syncthreads();
    }
    if (threadIdx.x == 0) cnt[bucket] = base;
}

// ---------------- grouped expert GEMM: BK=32, 4 blocks/CU, atomic epilogue ---
__global__ __launch_bounds__(256, 4)
void moe_gemm(const ushort* __restrict__ xbf, const ushort* __restrict__ WeT,
              const float* __restrict__ be, const int* __restrict__ cnt,
              const int* __restrict__ idxl, const float* __restrict__ wl,
              float* __restrict__ out) {
    __shared__ ushort Al[2][BM][BK2];     // 16 KB
    __shared__ ushort Bl[2][BM][BK2];     // 16 KB

    const int q8 = gridDim.x >> 3;
    const int W  = (blockIdx.x & 7) * q8 + (blockIdx.x >> 3);
    const int bucket = W >> 8;
    const int t  = (W >> 3) & 31;
    const int cT = W & 7;
    const int count = cnt[bucket];
    if (t * BM >= count) return;
    const int nrowsv = min(BM, count - t * BM);
    const int e  = bucket & 7;
    const int c0 = cT * BN;
    const int*   rows = idxl + (size_t)bucket * NR + t * BM;
    const float* wrow = wl   + (size_t)bucket * NR + t * BM;

    const int tid = threadIdx.x, wid = tid >> 6, lane = tid & 63;
    const int wr = (wid >> 1) * 64, wc = (wid & 1) * 64;
    const int l16 = lane & 15, lhi = lane >> 4;

    // staging: per wave, 2 gload16 for A (16 rows each) + 2 for B.
    // lane -> row r0 + (lane>>2), 16B chunk (lane&3), source-swizzled by
    // chunk' = chunk ^ ((row>>1)&3) = chunk ^ ((lane>>3)&3)  (r0 % 16 == 0)
    const int srow = lane >> 2;
    const int sch  = ((lane & 3) ^ ((lane >> 3) & 3)) * 8;   // ushort units
    const ushort* aptr[2];
    const ushort* bptr[2];
#pragma unroll
    for (int q = 0; q < 2; ++q) {
        int r = wid * 32 + q * 16 + srow;
        aptr[q] = xbf + (size_t)rows[min(r, nrowsv - 1)] * DIM + sch;
        int c = c0 + wid * 32 + q * 16 + srow;
        bptr[q] = WeT + ((size_t)(e * DIM + c)) * DIM + sch;
    }

    f32x4 acc[4][4];
#pragma unroll
    for (int m = 0; m < 4; ++m)
#pragma unroll
        for (int n = 0; n < 4; ++n) { f32x4 z = {0.f, 0.f, 0.f, 0.f}; acc[m][n] = z; }

    // prologue: stage tile 0 into buf 0 (4 loads per wave)
#pragma unroll
    for (int q = 0; q < 2; ++q) {
        gload16(aptr[q], &Al[0][wid * 32 + q * 16][0]);
        gload16(bptr[q], &Bl[0][wid * 32 + q * 16][0]);
    }

    const int chb = (lhi ^ ((l16 >> 1) & 3)) * 8;            // read-side swizzle
    const int NSTEP = DIM / BK2;                             // 32
    for (int s = 0; s < NSTEP; ++s) {
        const int buf = s & 1;
        if (s + 1 < NSTEP) {
            const int nb = buf ^ 1, k0 = (s + 1) * BK2;
#pragma unroll
            for (int q = 0; q < 2; ++q) {
                gload16(aptr[q] + k0, &Al[nb][wid * 32 + q * 16][0]);
                gload16(bptr[q] + k0, &Bl[nb][wid * 32 + q * 16][0]);
            }
            asm volatile("s_waitcnt vmcnt(4)" ::: "memory");  // current tile landed
        } else {
            asm volatile("s_waitcnt vmcnt(0)" ::: "memory");
        }
        __builtin_amdgcn_s_barrier();

        const ushort* Ab = &Al[buf][0][0];
        const ushort* Bb = &Bl[buf][0][0];
        bf16x8 af[4], bfr[4];
#pragma unroll
        for (int m = 0; m < 4; ++m)
            af[m] = *(const bf16x8*)(Ab + (wr + m * 16 + l16) * BK2 + chb);
#pragma unroll
        for (int n = 0; n < 4; ++n)
            bfr[n] = *(const bf16x8*)(Bb + (wc + n * 16 + l16) * BK2 + chb);
#pragma unroll
        for (int m = 0; m < 4; ++m)
#pragma unroll
            for (int n = 0; n < 4; ++n)
                acc[m][n] = __builtin_amdgcn_mfma_f32_16x16x32_bf16(af[m], bfr[n], acc[m][n], 0, 0, 0);

        asm volatile("s_waitcnt lgkmcnt(0)" ::: "memory");
        __builtin_amdgcn_s_barrier();
    }

    // epilogue: out += w * (acc + be), exactly 2 commutative adds per element
    float bev[4];
#pragma unroll
    for (int n = 0; n < 4; ++n) bev[n] = be[(size_t)e * DIM + c0 + wc + n * 16 + l16];
#pragma unroll
    for (int m = 0; m < 4; ++m) {
#pragma unroll
        for (int r = 0; r < 4; ++r) {
            int rl = wr + m * 16 + lhi * 4 + r;
            if (rl < nrowsv) {
                int   gr = rows[rl];
                float w  = wrow[rl];
                float* op = out + (size_t)gr * DIM + c0 + wc;
#pragma unroll
                for (int n = 0; n < 4; ++n)
                    atomicAdd(&op[n * 16 + l16], w * (acc[m][n][r] + bev[n]));
            }
        }
    }
}

extern "C" void kernel_launch(void* const* d_in, const int* in_sizes, int n_in,
                              void* d_out, int out_size, void* d_ws, size_t ws_size,
                              hipStream_t stream) {
    const float* x     = (const float*)d_in[0];
    const float* noise = (const float*)d_in[1];
    const float* Wg    = (const float*)d_in[2];
    const float* Wn    = (const float*)d_in[3];
    const float* We    = (const float*)d_in[4];
    const float* be    = (const float*)d_in[5];
    float* out = (float*)d_out;

    char* w = (char*)d_ws;
    size_t off = 256;
    int*      cnt   = (int*)w;
    int*      idxl  = (int*)(w + off);      off += (size_t)2 * NE * NR * 4;   // 256 KB
    float*    wl    = (float*)(w + off);    off += (size_t)2 * NE * NR * 4;   // 256 KB
    uint32_t* eid   = (uint32_t*)(w + off); off += (size_t)NR * 4;            // 16 KB
    float2*   wpair = (float2*)(w + off);   off += (size_t)NR * 8;            // 32 KB
    off = (off + 255) & ~(size_t)255;
    float*  WT  = (float*)(w + off);  off += (size_t)16 * DIM * 4;            // 64 KB
    ushort* xbf = (ushort*)(w + off); off += (size_t)NR * DIM * 2;            // 8 MB
    ushort* WeT = (ushort*)(w + off); off += (size_t)NE * DIM * DIM * 2;      // 16 MB

    k1_prep<<<520, 256, 0, stream>>>(Wg, Wn, WT, out);
    k2_main<<<3072, 256, 0, stream>>>(We, WeT, x, noise, WT, xbf, eid, wpair);
    bucket_build<<<16, 1024, 0, stream>>>(eid, wpair, cnt, idxl, wl);
    moe_gemm<<<16 * 32 * 8, 256, 0, stream>>>(xbf, WeT, be, cnt, idxl, wl, out);
}

// Round 7
// 87.047 us; speedup vs baseline: 1.0324x; 1.0324x over previous
//
#include <hip/hip_runtime.h>
#include <hip/hip_bf16.h>
#include <stdint.h>

#define NR   4096
#define DIM  1024
#define NE   8
#define BM   64
#define BN   128
#define BK   64

typedef __attribute__((ext_vector_type(8))) short  bf16x8;
typedef __attribute__((ext_vector_type(8))) ushort u16x8;
typedef __attribute__((ext_vector_type(4))) float  f32x4;

__device__ __forceinline__ ushort f2bf(float f) {
    union { __hip_bfloat16 h; ushort u; } cv;
    cv.h = __float2bfloat16(f);   // RNE
    return cv.u;
}

__device__ __forceinline__ void gload16(const void* g, void* l) {
    __builtin_amdgcn_global_load_lds(
        (const __attribute__((address_space(1))) unsigned int*)g,
        (__attribute__((address_space(3))) unsigned int*)l, 16, 0, 0);
}

// ---------------- K1: WT transpose (blocks 0..7) + zero out (blocks 8..519) --
__global__ __launch_bounds__(256)
void k1_prep(const float* __restrict__ Wg, const float* __restrict__ Wn,
             float* __restrict__ WT, float* __restrict__ out) {
    const int tid = threadIdx.x;
    if (blockIdx.x < 8) {
        const int k    = blockIdx.x * 128 + (tid >> 1);
        const int half = tid & 1;                     // 0 = Wg, 1 = Wn
        const float* src = half ? Wn : Wg;
        const float4* s4 = (const float4*)(src + (size_t)k * NE);
        float4 a = s4[0], b = s4[1];
        float* d = WT + (size_t)half * 8 * DIM;
        d[(size_t)0 * DIM + k] = a.x; d[(size_t)1 * DIM + k] = a.y;
        d[(size_t)2 * DIM + k] = a.z; d[(size_t)3 * DIM + k] = a.w;
        d[(size_t)4 * DIM + k] = b.x; d[(size_t)5 * DIM + k] = b.y;
        d[(size_t)6 * DIM + k] = b.z; d[(size_t)7 * DIM + k] = b.w;
    } else {
        const int vb = blockIdx.x - 8;                // 0..511
        float4 z = {0.f, 0.f, 0.f, 0.f};
        for (int i = vb * 256 + tid; i < NR * DIM / 4; i += 512 * 256)
            ((float4*)out)[i] = z;
    }
}

// ---------------- K2: We convert+transpose (blocks 0..2047) | gate (2048..3071)
__global__ __launch_bounds__(256)
void k2_main(const float* __restrict__ We, ushort* __restrict__ WeT,
             const float* __restrict__ x, const float* __restrict__ noise,
             const float* __restrict__ WT, ushort* __restrict__ xbf,
             uint32_t* __restrict__ eid, float2* __restrict__ wpair) {
    __shared__ float smem[64 * 68];                   // 17.4 KB, both roles
    const int tid = threadIdx.x;
    if (blockIdx.x < 2048) {
        // ---- conv role: We [e][k][c] f32 -> WeT [e][c][k] bf16 ----
        const int b  = blockIdx.x;                    // e*256 + kt*16 + ct
        const int e  = b >> 8, kt = (b >> 4) & 15, ct = b & 15;
        const float* src = We + ((size_t)e * DIM + (size_t)kt * 64) * DIM + ct * 64;
#pragma unroll
        for (int j = 0; j < 4; ++j) {
            int idx = tid + j * 256;
            int r = idx >> 4, c4 = idx & 15;
            *(float4*)&smem[r * 68 + c4 * 4] = *(const float4*)(src + (size_t)r * DIM + c4 * 4);
        }
        __syncthreads();
        ushort* dst = WeT + ((size_t)e * DIM + (size_t)ct * 64) * DIM + kt * 64;
#pragma unroll
        for (int j = 0; j < 2; ++j) {
            int u = tid + j * 256;
            int c = u >> 3, ch = u & 7;
            ushort tmp[8];
#pragma unroll
            for (int q = 0; q < 8; ++q) tmp[q] = f2bf(smem[(ch * 8 + q) * 68 + c]);
            *(u16x8*)(dst + (size_t)c * DIM + ch * 8) = *(u16x8*)tmp;
        }
    } else {
        // ---- gate role: one wave per row, no atomics ----
        const int w = tid >> 6, l = tid & 63;
        const int row = (blockIdx.x - 2048) * 4 + w;
        const float* xr = x + (size_t)row * DIM;

        float4 xv[4];
#pragma unroll
        for (int q = 0; q < 4; ++q) xv[q] = *(const float4*)(xr + q * 256 + l * 4);
#pragma unroll
        for (int q = 0; q < 4; ++q) {
            ushort4 xb;
            xb.x = f2bf(xv[q].x); xb.y = f2bf(xv[q].y);
            xb.z = f2bf(xv[q].z); xb.w = f2bf(xv[q].w);
            *(ushort4*)(xbf + (size_t)row * DIM + q * 256 + l * 4) = xb;
        }

        float acc[16];
#pragma unroll
        for (int u = 0; u < 16; ++u) {
            const float* wr_ = WT + (size_t)u * DIM + l * 4;
            float s = 0.f;
#pragma unroll
            for (int q = 0; q < 4; ++q) {
                float4 wv = *(const float4*)(wr_ + q * 256);
                s += xv[q].x * wv.x + xv[q].y * wv.y + xv[q].z * wv.z + xv[q].w * wv.w;
            }
            acc[u] = s;
        }
#pragma unroll
        for (int u = 0; u < 16; ++u) smem[(w * 64 + l) * 17 + u] = acc[u];
        asm volatile("s_waitcnt lgkmcnt(0)" ::: "memory");
        const int c = l >> 4, u = l & 15;
        float v = 0.f;
#pragma unroll
        for (int i = 0; i < 16; ++i) v += smem[(w * 64 + c * 16 + i) * 17 + u];
        v += __shfl_xor(v, 16, 64);
        v += __shfl_xor(v, 32, 64);

        const int e = l & 7;
        float ag = __shfl(v, e, 64);
        float an = __shfl(v, e + 8, 64);
        float sp = (an > 0.f) ? (an + log1pf(expf(-an))) : log1pf(expf(an));
        float H  = ag + noise[e] * sp;

        float Hh[8];
#pragma unroll
        for (int k = 0; k < 8; ++k) Hh[k] = __shfl(H, k, 64);
        if (l == 0) {
            int e0 = 0; float v0 = Hh[0];
#pragma unroll
            for (int k = 1; k < 8; ++k) if (Hh[k] > v0) { v0 = Hh[k]; e0 = k; }
            int e1 = -1; float v1 = 0.f;
#pragma unroll
            for (int k = 0; k < 8; ++k)
                if (k != e0 && (e1 < 0 || Hh[k] > v1)) { v1 = Hh[k]; e1 = k; }
            float rr = expf(v1 - v0);
            float w0 = 1.f / (1.f + rr), w1 = 1.f - w0;
            eid[row] = (uint32_t)e0 | ((uint32_t)e1 << 8);
            float2 wp; wp.x = w0; wp.y = w1;
            wpair[row] = wp;
        }
    }
}

// ---------------- bucket build: deterministic compaction ---------------------
__global__ __launch_bounds__(1024)
void bucket_build(const uint32_t* __restrict__ eid, const float2* __restrict__ wpair,
                  int* __restrict__ cnt, int* __restrict__ idxl, float* __restrict__ wl) {
    const int bucket = blockIdx.x;          // 0..15
    const int slot = bucket >> 3, ex = bucket & 7;
    __shared__ int base;
    __shared__ int wsum[16];
    if (threadIdx.x == 0) base = 0;
    const int wid = threadIdx.x >> 6, lane = threadIdx.x & 63;
    int* bidx = idxl + (size_t)bucket * NR;
    float* bwl = wl + (size_t)bucket * NR;

    for (int c0 = 0; c0 < NR; c0 += 1024) {
        const int row = c0 + threadIdx.x;
        const uint32_t em = eid[row];
        const int e = slot ? (int)((em >> 8) & 255u) : (int)(em & 255u);
        const bool m = (e == ex);
        const unsigned long long bal = __ballot(m);
        if (lane == 0) wsum[wid] = __popcll(bal);
        __syncthreads();
        int wbase = base;
        for (int i = 0; i < wid; ++i) wbase += wsum[i];
        const int pos = wbase + __popcll(bal & ((1ull << lane) - 1ull));
        if (m) {
            bidx[pos] = row;
            float2 wp = wpair[row];
            bwl[pos]  = slot ? wp.y : wp.x;
        }
        __syncthreads();
        if (threadIdx.x == 0) {
            int s = 0;
#pragma unroll
            for (int i = 0; i < 16; ++i) s += wsum[i];
            base += s;
        }
        __syncthreads();
    }
    if (threadIdx.x == 0) cnt[bucket] = base;
}

// ---------------- grouped expert GEMM: 64x128 tiles, worklist grid -----------
// grid = 144 items x 8 colT (XCD-swizzled). Each block maps item->(bucket,tile)
// via prefix scan over cnt. 3 blocks/CU (48 KB LDS), BK=64, vmcnt(6) prefetch.
__global__ __launch_bounds__(256, 3)
void moe_gemm(const ushort* __restrict__ xbf, const ushort* __restrict__ WeT,
              const float* __restrict__ be, const int* __restrict__ cnt,
              const int* __restrict__ idxl, const float* __restrict__ wl,
              float* __restrict__ out) {
    __shared__ ushort Al[2][BM][BK];     // 16 KB
    __shared__ ushort Bl[2][BN][BK];     // 32 KB

    const int q8 = gridDim.x >> 3;
    const int W  = (blockIdx.x & 7) * q8 + (blockIdx.x >> 3);
    const int item = W >> 3, cT = W & 7;

    // worklist: item -> (bucket, row-tile) via prefix of ceil(cnt/BM)
    int bucket = -1, tile = 0, accp = 0;
#pragma unroll
    for (int b = 0; b < 16; ++b) {
        int t = (cnt[b] + BM - 1) >> 6;
        if (bucket < 0 && item < accp + t) { bucket = b; tile = item - accp; }
        accp += t;
    }
    if (bucket < 0) return;
    const int count  = cnt[bucket];
    const int nrowsv = min(BM, count - tile * BM);
    const int e  = bucket & 7;
    const int c0 = cT * BN;
    const int*   rows = idxl + (size_t)bucket * NR + tile * BM;
    const float* wrow = wl   + (size_t)bucket * NR + tile * BM;

    const int tid = threadIdx.x, wid = tid >> 6, lane = tid & 63;
    const int wr = (wid >> 1) * 32, wc = (wid & 1) * 64;
    const int l16 = lane & 15, lhi = lane >> 4;

    // staging: row = base + (lane>>3), LDS slot = lane&7 (linear dest);
    // source chunk = slot ^ (row&7) = (lane&7) ^ ((lane>>3)&7)
    const int schunk = ((lane & 7) ^ ((lane >> 3) & 7)) * 8;   // ushort offset
    const ushort* aptr[2];
    const ushort* bptr[4];
#pragma unroll
    for (int q = 0; q < 2; ++q) {
        int r = q * 32 + wid * 8 + (lane >> 3);
        aptr[q] = xbf + (size_t)rows[min(r, nrowsv - 1)] * DIM + schunk;
    }
#pragma unroll
    for (int q = 0; q < 4; ++q) {
        int c = c0 + q * 32 + wid * 8 + (lane >> 3);
        bptr[q] = WeT + ((size_t)(e * DIM + c)) * DIM + schunk;
    }

    f32x4 acc[2][4];
#pragma unroll
    for (int m = 0; m < 2; ++m)
#pragma unroll
        for (int n = 0; n < 4; ++n) { f32x4 z = {0.f, 0.f, 0.f, 0.f}; acc[m][n] = z; }

    // prologue: stage tile 0 into buf 0 (6 loads per wave)
#pragma unroll
    for (int q = 0; q < 2; ++q) gload16(aptr[q], &Al[0][q * 32 + wid * 8][0]);
#pragma unroll
    for (int q = 0; q < 4; ++q) gload16(bptr[q], &Bl[0][q * 32 + wid * 8][0]);

    const int NSTEP = DIM / BK;                                // 16
    for (int s = 0; s < NSTEP; ++s) {
        const int buf = s & 1;
        if (s + 1 < NSTEP) {
            const int nb = buf ^ 1, k0 = (s + 1) * BK;
#pragma unroll
            for (int q = 0; q < 2; ++q) gload16(aptr[q] + k0, &Al[nb][q * 32 + wid * 8][0]);
#pragma unroll
            for (int q = 0; q < 4; ++q) gload16(bptr[q] + k0, &Bl[nb][q * 32 + wid * 8][0]);
            asm volatile("s_waitcnt vmcnt(6)" ::: "memory");   // current tile landed
        } else {
            asm volatile("s_waitcnt vmcnt(0)" ::: "memory");
        }
        __builtin_amdgcn_s_barrier();

        // read-side swizzle: slot = j ^ (row&7) = j ^ (l16&7), j = h*4 + lhi
#pragma unroll
        for (int h = 0; h < 2; ++h) {
            const int slot = ((h * 4 + lhi) ^ (l16 & 7)) * 8;
            bf16x8 af[2], bfr[4];
#pragma unroll
            for (int m = 0; m < 2; ++m)
                af[m] = *(const bf16x8*)(&Al[buf][wr + m * 16 + l16][0] + slot);
#pragma unroll
            for (int n = 0; n < 4; ++n)
                bfr[n] = *(const bf16x8*)(&Bl[buf][wc + n * 16 + l16][0] + slot);
#pragma unroll
            for (int m = 0; m < 2; ++m)
#pragma unroll
                for (int n = 0; n < 4; ++n)
                    acc[m][n] = __builtin_amdgcn_mfma_f32_16x16x32_bf16(af[m], bfr[n], acc[m][n], 0, 0, 0);
        }
        asm volatile("s_waitcnt lgkmcnt(0)" ::: "memory");
        __builtin_amdgcn_s_barrier();
    }

    // epilogue: out += w * (acc + be); exactly 2 commutative adds per element
    float bev[4];
#pragma unroll
    for (int n = 0; n < 4; ++n) bev[n] = be[(size_t)e * DIM + c0 + wc + n * 16 + l16];
#pragma unroll
    for (int m = 0; m < 2; ++m) {
#pragma unroll
        for (int r = 0; r < 4; ++r) {
            int rl = wr + m * 16 + lhi * 4 + r;
            if (rl < nrowsv) {
                int   gr = rows[rl];
                float w  = wrow[rl];
                float* op = out + (size_t)gr * DIM + c0 + wc;
#pragma unroll
                for (int n = 0; n < 4; ++n)
                    atomicAdd(&op[n * 16 + l16], w * (acc[m][n][r] + bev[n]));
            }
        }
    }
}

extern "C" void kernel_launch(void* const* d_in, const int* in_sizes, int n_in,
                              void* d_out, int out_size, void* d_ws, size_t ws_size,
                              hipStream_t stream) {
    const float* x     = (const float*)d_in[0];
    const float* noise = (const float*)d_in[1];
    const float* Wg    = (const float*)d_in[2];
    const float* Wn    = (const float*)d_in[3];
    const float* We    = (const float*)d_in[4];
    const float* be    = (const float*)d_in[5];
    float* out = (float*)d_out;

    char* w = (char*)d_ws;
    size_t off = 256;
    int*      cnt   = (int*)w;
    int*      idxl  = (int*)(w + off);      off += (size_t)2 * NE * NR * 4;   // 256 KB
    float*    wl    = (float*)(w + off);    off += (size_t)2 * NE * NR * 4;   // 256 KB
    uint32_t* eid   = (uint32_t*)(w + off); off += (size_t)NR * 4;            // 16 KB
    float2*   wpair = (float2*)(w + off);   off += (size_t)NR * 8;            // 32 KB
    off = (off + 255) & ~(size_t)255;
    float*  WT  = (float*)(w + off);  off += (size_t)16 * DIM * 4;            // 64 KB
    ushort* xbf = (ushort*)(w + off); off += (size_t)NR * DIM * 2;            // 8 MB
    ushort* WeT = (ushort*)(w + off); off += (size_t)NE * DIM * DIM * 2;      // 16 MB

    k1_prep<<<520, 256, 0, stream>>>(Wg, Wn, WT, out);
    k2_main<<<3072, 256, 0, stream>>>(We, WeT, x, noise, WT, xbf, eid, wpair);
    bucket_build<<<16, 1024, 0, stream>>>(eid, wpair, cnt, idxl, wl);
    moe_gemm<<<144 * 8, 256, 0, stream>>>(xbf, WeT, be, cnt, idxl, wl, out);
}

// Round 8
// 85.379 us; speedup vs baseline: 1.0526x; 1.0195x over previous
//
#include <hip/hip_runtime.h>
#include <hip/hip_bf16.h>
#include <stdint.h>

#define NR   4096
#define DIM  1024
#define NE   8
#define BM   128
#define BN   128
#define BK   32

typedef __attribute__((ext_vector_type(8))) short  bf16x8;
typedef __attribute__((ext_vector_type(8))) ushort u16x8;
typedef __attribute__((ext_vector_type(4))) float  f32x4;

__device__ __forceinline__ ushort f2bf(float f) {
    union { __hip_bfloat16 h; ushort u; } cv;
    cv.h = __float2bfloat16(f);   // RNE
    return cv.u;
}

__device__ __forceinline__ void gload16(const void* g, void* l) {
    __builtin_amdgcn_global_load_lds(
        (const __attribute__((address_space(1))) unsigned int*)g,
        (__attribute__((address_space(3))) unsigned int*)l, 16, 0, 0);
}

// ---------------- K1: WT transpose (blocks 0..7) + zero out (blocks 8..519) --
__global__ __launch_bounds__(256)
void k1_prep(const float* __restrict__ Wg, const float* __restrict__ Wn,
             float* __restrict__ WT, float* __restrict__ out) {
    const int tid = threadIdx.x;
    if (blockIdx.x < 8) {
        const int k    = blockIdx.x * 128 + (tid >> 1);
        const int half = tid & 1;                     // 0 = Wg, 1 = Wn
        const float* src = half ? Wn : Wg;
        const float4* s4 = (const float4*)(src + (size_t)k * NE);
        float4 a = s4[0], b = s4[1];
        float* d = WT + (size_t)half * 8 * DIM;
        d[(size_t)0 * DIM + k] = a.x; d[(size_t)1 * DIM + k] = a.y;
        d[(size_t)2 * DIM + k] = a.z; d[(size_t)3 * DIM + k] = a.w;
        d[(size_t)4 * DIM + k] = b.x; d[(size_t)5 * DIM + k] = b.y;
        d[(size_t)6 * DIM + k] = b.z; d[(size_t)7 * DIM + k] = b.w;
    } else {
        const int vb = blockIdx.x - 8;                // 0..511
        float4 z = {0.f, 0.f, 0.f, 0.f};
        for (int i = vb * 256 + tid; i < NR * DIM / 4; i += 512 * 256)
            ((float4*)out)[i] = z;
    }
}

// ---------------- K2: We convert+transpose (blocks 0..2047) | gate (2048..3071)
__global__ __launch_bounds__(256)
void k2_main(const float* __restrict__ We, ushort* __restrict__ WeT,
             const float* __restrict__ x, const float* __restrict__ noise,
             const float* __restrict__ WT, ushort* __restrict__ xbf,
             uint32_t* __restrict__ eid, float2* __restrict__ wpair) {
    __shared__ float smem[64 * 68];                   // 17.4 KB, both roles
    const int tid = threadIdx.x;
    if (blockIdx.x < 2048) {
        // ---- conv role: We [e][k][c] f32 -> WeT [e][c][k] bf16 ----
        const int b  = blockIdx.x;                    // e*256 + kt*16 + ct
        const int e  = b >> 8, kt = (b >> 4) & 15, ct = b & 15;
        const float* src = We + ((size_t)e * DIM + (size_t)kt * 64) * DIM + ct * 64;
#pragma unroll
        for (int j = 0; j < 4; ++j) {
            int idx = tid + j * 256;
            int r = idx >> 4, c4 = idx & 15;
            *(float4*)&smem[r * 68 + c4 * 4] = *(const float4*)(src + (size_t)r * DIM + c4 * 4);
        }
        __syncthreads();
        ushort* dst = WeT + ((size_t)e * DIM + (size_t)ct * 64) * DIM + kt * 64;
#pragma unroll
        for (int j = 0; j < 2; ++j) {
            int u = tid + j * 256;
            int c = u >> 3, ch = u & 7;
            ushort tmp[8];
#pragma unroll
            for (int q = 0; q < 8; ++q) tmp[q] = f2bf(smem[(ch * 8 + q) * 68 + c]);
            *(u16x8*)(dst + (size_t)c * DIM + ch * 8) = *(u16x8*)tmp;
        }
    } else {
        // ---- gate role: one wave per row, no atomics ----
        const int w = tid >> 6, l = tid & 63;
        const int row = (blockIdx.x - 2048) * 4 + w;
        const float* xr = x + (size_t)row * DIM;

        float4 xv[4];
#pragma unroll
        for (int q = 0; q < 4; ++q) xv[q] = *(const float4*)(xr + q * 256 + l * 4);
#pragma unroll
        for (int q = 0; q < 4; ++q) {
            ushort4 xb;
            xb.x = f2bf(xv[q].x); xb.y = f2bf(xv[q].y);
            xb.z = f2bf(xv[q].z); xb.w = f2bf(xv[q].w);
            *(ushort4*)(xbf + (size_t)row * DIM + q * 256 + l * 4) = xb;
        }

        float acc[16];
#pragma unroll
        for (int u = 0; u < 16; ++u) {
            const float* wr_ = WT + (size_t)u * DIM + l * 4;
            float s = 0.f;
#pragma unroll
            for (int q = 0; q < 4; ++q) {
                float4 wv = *(const float4*)(wr_ + q * 256);
                s += xv[q].x * wv.x + xv[q].y * wv.y + xv[q].z * wv.z + xv[q].w * wv.w;
            }
            acc[u] = s;
        }
#pragma unroll
        for (int u = 0; u < 16; ++u) smem[(w * 64 + l) * 17 + u] = acc[u];
        asm volatile("s_waitcnt lgkmcnt(0)" ::: "memory");
        const int c = l >> 4, u = l & 15;
        float v = 0.f;
#pragma unroll
        for (int i = 0; i < 16; ++i) v += smem[(w * 64 + c * 16 + i) * 17 + u];
        v += __shfl_xor(v, 16, 64);
        v += __shfl_xor(v, 32, 64);

        const int e = l & 7;
        float ag = __shfl(v, e, 64);
        float an = __shfl(v, e + 8, 64);
        float sp = (an > 0.f) ? (an + log1pf(expf(-an))) : log1pf(expf(an));
        float H  = ag + noise[e] * sp;

        float Hh[8];
#pragma unroll
        for (int k = 0; k < 8; ++k) Hh[k] = __shfl(H, k, 64);
        if (l == 0) {
            int e0 = 0; float v0 = Hh[0];
#pragma unroll
            for (int k = 1; k < 8; ++k) if (Hh[k] > v0) { v0 = Hh[k]; e0 = k; }
            int e1 = -1; float v1 = 0.f;
#pragma unroll
            for (int k = 0; k < 8; ++k)
                if (k != e0 && (e1 < 0 || Hh[k] > v1)) { v1 = Hh[k]; e1 = k; }
            float rr = expf(v1 - v0);
            float w0 = 1.f / (1.f + rr), w1 = 1.f - w0;
            eid[row] = (uint32_t)e0 | ((uint32_t)e1 << 8);
            float2 wp; wp.x = w0; wp.y = w1;
            wpair[row] = wp;
        }
    }
}

// ---------------- bucket build: deterministic compaction ---------------------
__global__ __launch_bounds__(1024)
void bucket_build(const uint32_t* __restrict__ eid, const float2* __restrict__ wpair,
                  int* __restrict__ cnt, int* __restrict__ idxl, float* __restrict__ wl) {
    const int bucket = blockIdx.x;          // 0..15
    const int slot = bucket >> 3, ex = bucket & 7;
    __shared__ int base;
    __shared__ int wsum[16];
    if (threadIdx.x == 0) base = 0;
    const int wid = threadIdx.x >> 6, lane = threadIdx.x & 63;
    int* bidx = idxl + (size_t)bucket * NR;
    float* bwl = wl + (size_t)bucket * NR;

    for (int c0 = 0; c0 < NR; c0 += 1024) {
        const int row = c0 + threadIdx.x;
        const uint32_t em = eid[row];
        const int e = slot ? (int)((em >> 8) & 255u) : (int)(em & 255u);
        const bool m = (e == ex);
        const unsigned long long bal = __ballot(m);
        if (lane == 0) wsum[wid] = __popcll(bal);
        __syncthreads();
        int wbase = base;
        for (int i = 0; i < wid; ++i) wbase += wsum[i];
        const int pos = wbase + __popcll(bal & ((1ull << lane) - 1ull));
        if (m) {
            bidx[pos] = row;
            float2 wp = wpair[row];
            bwl[pos]  = slot ? wp.y : wp.x;
        }
        __syncthreads();
        if (threadIdx.x == 0) {
            int s = 0;
#pragma unroll
            for (int i = 0; i < 16; ++i) s += wsum[i];
            base += s;
        }
        __syncthreads();
    }
    if (threadIdx.x == 0) cnt[bucket] = base;
}

// ---------------- grouped expert GEMM: 128x128, BK=32, ring-3 LDS ------------
// Counted vmcnt keeps 2 tiles in flight across barriers (T4). 3 blocks/CU.
// LDS swizzle: slot = chunk ^ ((row ^ (row>>2)) & 3)  (2 lanes/bank = free);
// applied inversely on the gload SOURCE address, XOR-applied on ds_read.
__global__ __launch_bounds__(256, 3)
void moe_gemm(const ushort* __restrict__ xbf, const ushort* __restrict__ WeT,
              const float* __restrict__ be, const int* __restrict__ cnt,
              const int* __restrict__ idxl, const float* __restrict__ wl,
              float* __restrict__ out) {
    __shared__ ushort lds[3][256][BK];    // per buf: rows 0..127 = A, 128..255 = B

    const int q8 = gridDim.x >> 3;
    const int W  = (blockIdx.x & 7) * q8 + (blockIdx.x >> 3);
    const int item = W >> 3, cT = W & 7;

    // worklist: item -> (bucket, row-tile) via prefix of ceil(cnt/BM)
    int bucket = -1, tile = 0, accp = 0;
#pragma unroll
    for (int b = 0; b < 16; ++b) {
        int t = (cnt[b] + BM - 1) >> 7;
        if (bucket < 0 && item < accp + t) { bucket = b; tile = item - accp; }
        accp += t;
    }
    if (bucket < 0) return;
    const int count  = cnt[bucket];
    const int nrowsv = min(BM, count - tile * BM);
    const int e  = bucket & 7;
    const int c0 = cT * BN;
    const int*   rows = idxl + (size_t)bucket * NR + tile * BM;
    const float* wrow = wl   + (size_t)bucket * NR + tile * BM;

    const int tid = threadIdx.x, wid = tid >> 6, lane = tid & 63;
    const int l16 = lane & 15, lhi = lane >> 4;
    const int wr = (wid >> 1) * 64, wc = (wid & 1) * 64;

    // ---- staging source pointers (per-lane, inverse-swizzled chunk) ----
    const int lr   = lane >> 2;                               // row-within-16
    const int fs   = ((lane >> 2) ^ (lane >> 4)) & 3;         // f(row) at stage
    const int csrc = ((lane & 3) ^ fs) * 8;                   // ushort offset
    const ushort* aptr[2];
    const ushort* bptr[2];
#pragma unroll
    for (int p = 0; p < 2; ++p) {
        int ridx = p * 64 + wid * 16 + lr;
        int gr   = rows[min(ridx, nrowsv - 1)];
        aptr[p]  = xbf + (size_t)gr * DIM + csrc;
        int col  = c0 + p * 64 + wid * 16 + lr;
        bptr[p]  = WeT + ((size_t)(e * DIM + col)) * DIM + csrc;
    }

    f32x4 acc[4][4];
#pragma unroll
    for (int m = 0; m < 4; ++m)
#pragma unroll
        for (int n = 0; n < 4; ++n) { f32x4 z = {0.f, 0.f, 0.f, 0.f}; acc[m][n] = z; }

#define STAGE(T, BUF) do {                                                   \
    const int _k0 = (T) * BK;                                                \
    ushort* _b = &lds[(BUF)][0][0];                                          \
    _Pragma("unroll")                                                        \
    for (int p = 0; p < 2; ++p) {                                            \
        gload16(aptr[p] + _k0, _b + (p * 64 + wid * 16) * BK);               \
        gload16(bptr[p] + _k0, _b + (128 + p * 64 + wid * 16) * BK);         \
    }                                                                        \
} while (0)

    const int fr    = (l16 ^ (l16 >> 2)) & 3;                 // f(row) at read
    const int rslot = (lhi ^ fr) * 8;                         // ushort offset

    const int NS = DIM / BK;                                  // 32
    STAGE(0, 0);
    STAGE(1, 1);
    int c = 0, s = 2;
    for (int t = 0; t < NS; ++t) {
        if (t + 2 < NS) {
            STAGE(t + 2, s);
            asm volatile("s_waitcnt vmcnt(8)" ::: "memory");  // tile t landed
        } else if (t + 1 < NS) {
            asm volatile("s_waitcnt vmcnt(4)" ::: "memory");
        } else {
            asm volatile("s_waitcnt vmcnt(0)" ::: "memory");
        }
        __builtin_amdgcn_s_barrier();

        const ushort* base = &lds[c][0][0];
        bf16x8 af[4], bfr[4];
#pragma unroll
        for (int m = 0; m < 4; ++m)
            af[m] = *(const bf16x8*)(base + (wr + m * 16 + l16) * BK + rslot);
#pragma unroll
        for (int n = 0; n < 4; ++n)
            bfr[n] = *(const bf16x8*)(base + (128 + wc + n * 16 + l16) * BK + rslot);
        __builtin_amdgcn_s_setprio(1);
#pragma unroll
        for (int m = 0; m < 4; ++m)
#pragma unroll
            for (int n = 0; n < 4; ++n)
                acc[m][n] = __builtin_amdgcn_mfma_f32_16x16x32_bf16(af[m], bfr[n], acc[m][n], 0, 0, 0);
        __builtin_amdgcn_s_setprio(0);

        asm volatile("s_waitcnt lgkmcnt(0)" ::: "memory");    // reads retired
        __builtin_amdgcn_s_barrier();                         // before re-stage
        s = c; c = (c == 2) ? 0 : c + 1;
    }
#undef STAGE

    // epilogue: out += w * (acc + be); exactly 2 commutative adds per element
    float bev[4];
#pragma unroll
    for (int n = 0; n < 4; ++n) bev[n] = be[(size_t)e * DIM + c0 + wc + n * 16 + l16];
#pragma unroll
    for (int m = 0; m < 4; ++m) {
#pragma unroll
        for (int r = 0; r < 4; ++r) {
            int rl = wr + m * 16 + lhi * 4 + r;
            if (rl < nrowsv) {
                int   gr = rows[rl];
                float w  = wrow[rl];
                float* op = out + (size_t)gr * DIM + c0 + wc;
#pragma unroll
                for (int n = 0; n < 4; ++n)
                    atomicAdd(&op[n * 16 + l16], w * (acc[m][n][r] + bev[n]));
            }
        }
    }
}

extern "C" void kernel_launch(void* const* d_in, const int* in_sizes, int n_in,
                              void* d_out, int out_size, void* d_ws, size_t ws_size,
                              hipStream_t stream) {
    const float* x     = (const float*)d_in[0];
    const float* noise = (const float*)d_in[1];
    const float* Wg    = (const float*)d_in[2];
    const float* Wn    = (const float*)d_in[3];
    const float* We    = (const float*)d_in[4];
    const float* be    = (const float*)d_in[5];
    float* out = (float*)d_out;

    char* w = (char*)d_ws;
    size_t off = 256;
    int*      cnt   = (int*)w;
    int*      idxl  = (int*)(w + off);      off += (size_t)2 * NE * NR * 4;   // 256 KB
    float*    wl    = (float*)(w + off);    off += (size_t)2 * NE * NR * 4;   // 256 KB
    uint32_t* eid   = (uint32_t*)(w + off); off += (size_t)NR * 4;            // 16 KB
    float2*   wpair = (float2*)(w + off);   off += (size_t)NR * 8;            // 32 KB
    off = (off + 255) & ~(size_t)255;
    float*  WT  = (float*)(w + off);  off += (size_t)16 * DIM * 4;            // 64 KB
    ushort* xbf = (ushort*)(w + off); off += (size_t)NR * DIM * 2;            // 8 MB
    ushort* WeT = (ushort*)(w + off); off += (size_t)NE * DIM * DIM * 2;      // 16 MB

    k1_prep<<<520, 256, 0, stream>>>(Wg, Wn, WT, out);
    k2_main<<<3072, 256, 0, stream>>>(We, WeT, x, noise, WT, xbf, eid, wpair);
    bucket_build<<<16, 1024, 0, stream>>>(eid, wpair, cnt, idxl, wl);
    moe_gemm<<<80 * 8, 256, 0, stream>>>(xbf, WeT, be, cnt, idxl, wl, out);
}